// Round 8
// baseline (203.819 us; speedup 1.0000x reference)
//
#include <hip/hip_runtime.h>

#define NB 64
#define NN 100
#define DL 32
#define BN (NB * NN)  // 6400

typedef _Float16 f16x8 __attribute__((ext_vector_type(8)));
typedef float f32x4 __attribute__((ext_vector_type(4)));

static __device__ __forceinline__ float lrelu(float x) { return fmaxf(x, 0.1f * x); }
static __device__ __forceinline__ f32x4 ld4(const float* p) { return *(const f32x4*)p; }
static __device__ __forceinline__ float hsum4(f32x4 v) { return v[0] + v[1] + v[2] + v[3]; }

// Fused: h = x@lin_w+lin_b, U/V for step 0 (V stored f16), W1 B-fragment prep.
// Blocks 0..1599: 4 (b,n) rows each. Blocks 1600..1601: PW for step 0/1.
__global__ __launch_bounds__(256) void k_pre(
    const float* __restrict__ x, const float* __restrict__ lw, const float* __restrict__ lb,
    const float* __restrict__ ew0, const float* __restrict__ eb0,
    const float* __restrict__ w1a, const float* __restrict__ w1b,
    float* __restrict__ h, float* __restrict__ U, _Float16* __restrict__ V,
    _Float16* __restrict__ PW) {
    int blk = blockIdx.x;
    int t = threadIdx.x;
    if (blk >= 1600) {  // B-fragment swizzle: PW[step][kt][hf][lane][jj]
        int step = blk - 1600;
        const float* w1 = step ? w1b : w1a;
        _Float16* dst = PW + step * 4096;
#pragma unroll
        for (int u = 0; u < 16; ++u) {
            int idx = t * 16 + u;
            int jj = idx & 7, lane = (idx >> 3) & 63, hf = (idx >> 9) & 1, kt = idx >> 10;
            int c = hf * 32 + (lane >> 4) * 8 + jj;
            int k = kt * 16 + (lane & 15);
            dst[idx] = (_Float16)w1[c * 64 + k];
        }
        return;
    }
    __shared__ float xs[DL];
    __shared__ float hs[4][DL];
    int row0 = blk * 4;
    int b = row0 / NN;  // 4-row group never crosses a batch boundary (100 % 4 == 0)
    if (t < DL) xs[t] = x[b * DL + t];
    __syncthreads();
    if (t < 128) {
        int ni = t >> 5, c = t & 31;
        int n = (row0 + ni) % NN;
        float s = lb[n * DL + c];
#pragma unroll
        for (int cc = 0; cc < DL; ++cc) s += xs[cc] * lw[cc * 3200 + n * DL + c];
        hs[ni][c] = s;
        h[(row0 + ni) * DL + c] = s;
    }
    __syncthreads();
#pragma unroll
    for (int r = 0; r < 2; ++r) {
        int o = r * 256 + t;  // 0..511 : 4 rows x (64 U + 64 V)
        int ni = o >> 7, kw = o & 127;
        int which = kw >> 6, k = kw & 63;
        const float* wp = ew0 + (which ? DL * 64 : 0) + k;
        float s = which ? 0.f : eb0[k];
#pragma unroll
        for (int c = 0; c < DL; ++c) s += hs[ni][c] * wp[c * 64];
        if (which) V[(row0 + ni) * 64 + k] = (_Float16)s;
        else       U[(row0 + ni) * 64 + k] = s;
    }
}

// One (b,i) row per 128-thread block; TWO waves split the j-range.
// R7 lesson: 1600 4-wave blocks = 6.25 blocks/CU, no queue -> 28% occupancy,
// latency exposed. This grid gives 6400 blocks (12,800 waves = 50 waves/CU
// demand vs ~32 cap -> real queue) and halves per-wave critical path:
//   wave0: j-tiles 0..2 + dist j 0..63;  wave1: j-tiles 3..6 (+tail) + dist 48..111
//   (dist overlap 48..63 is a benign identical-value double-write).
// Halves summed via LDS aggp. Epilogue split across the 2 waves.
// Kept: no min-waves bound (R4/R5 spill), opaque-pb anti-hoist (R7),
// packed-f16 P-build + f16 V (R6).
template <int FINAL>
__global__ __launch_bounds__(128) void k_edge(
    const float* __restrict__ h, const float* __restrict__ U, const _Float16* __restrict__ V,
    const float* __restrict__ w0, const _Float16* __restrict__ PW,
    const float* __restrict__ b1,
    const float* __restrict__ w0n, const float* __restrict__ b0n,
    const float* __restrict__ w1n, const float* __restrict__ b1n,
    const float* __restrict__ wA, const float* __restrict__ bA,
    float* __restrict__ hout, float* __restrict__ Uo, _Float16* __restrict__ Vo,
    float* __restrict__ out) {
    __shared__ __align__(16) _Float16 pwl[4096];
    __shared__ float sdist[112];
    __shared__ __align__(16) float sxin[32];
    __shared__ __align__(16) float aggp[2][64];
    __shared__ __align__(16) float red[2][64];
    __shared__ __align__(16) float st0[64];
    __shared__ __align__(16) float sh2[32];

    int t = threadIdx.x;
    {  // stage W1 B-fragments (128 threads x 4 f16x8 = 512)
        const f16x8* srcp = (const f16x8*)PW;
        f16x8* dstp = (f16x8*)pwl;
        dstp[t] = srcp[t];
        dstp[t + 128] = srcp[t + 128];
        dstp[t + 256] = srcp[t + 256];
        dstp[t + 384] = srcp[t + 384];
    }
    int w = t >> 6, lane = t & 63, q = lane >> 4, kk = lane & 15;
    int bi = blockIdx.x;
    int b = bi / NN;

    if (t < 32) sxin[t] = h[bi * DL + t];

    // distances (split): wave0 j 0..63, wave1 j 48..111; 8 lanes per j, shfl-reduce
    {
        int g = lane >> 3, r = lane & 7;
        int jbase = w * 48;
        f32x4 hi4 = ld4(h + bi * DL + r * 4);
        const float* hb = h + b * NN * DL;
#pragma unroll
        for (int it = 0; it < 8; ++it) {
            int j = jbase + it * 8 + g;
            int jc = j < NN ? j : NN - 1;
            f32x4 hj4 = ld4(hb + jc * DL + r * 4);
            f32x4 dd = hi4 - hj4;
            float s = dd[0] * dd[0] + dd[1] * dd[1] + dd[2] * dd[2] + dd[3] * dd[3];
            s += __shfl_xor(s, 1);
            s += __shfl_xor(s, 2);
            s += __shfl_xor(s, 4);
            if (r == 0) sdist[j] = sqrtf(s + 1e-12f);
        }
    }

    int c0 = q * 8;  // this lane's channel base
    // u (U_i + b0 folded) and wd as packed f16 (8 VGPRs each)
    f16x8 ulo, uhi, wdlo, wdhi;
    {
        const float* Up = U + (size_t)bi * 64;
        f32x4 a0 = ld4(Up + c0), a1 = ld4(Up + c0 + 4);
        f32x4 a2 = ld4(Up + 32 + c0), a3 = ld4(Up + 36 + c0);
        const float* wd = w0 + 64 * 64;
        f32x4 d0 = ld4(wd + c0), d1 = ld4(wd + c0 + 4);
        f32x4 d2 = ld4(wd + 32 + c0), d3 = ld4(wd + 36 + c0);
#pragma unroll
        for (int i = 0; i < 4; ++i) {
            ulo[i] = (_Float16)a0[i];  ulo[i + 4] = (_Float16)a1[i];
            uhi[i] = (_Float16)a2[i];  uhi[i + 4] = (_Float16)a3[i];
            wdlo[i] = (_Float16)d0[i]; wdlo[i + 4] = (_Float16)d1[i];
            wdhi[i] = (_Float16)d2[i]; wdhi[i + 4] = (_Float16)d3[i];
        }
    }
    float b1k[4];
#pragma unroll
    for (int kt = 0; kt < 4; ++kt) b1k[kt] = b1[kt * 16 + kk];
    float m6 = (q == 0) ? 1.f : 0.f;  // tile 6: only rows 96..99 (q==0) valid

    const _Float16* Vb = V + (size_t)b * NN * 64;
    int jt0 = w ? 3 : 0;
    f16x8 vlo, vhi;
    {   // prefetch this wave's first tile (j = jt0*16+kk < 100, no clamp)
        const _Float16* vr = Vb + (jt0 * 16 + kk) * 64 + c0;
        vlo = *(const f16x8*)vr;
        vhi = *(const f16x8*)(vr + 32);
    }

    __syncthreads();  // pwl ready (sdist/sxin uses are ordered separately)
    float dj = sdist[jt0 * 16 + kk];

    float sacc[4] = {0.f, 0.f, 0.f, 0.f};
    unsigned pb = 0;  // opaque LDS byte-offset: blocks cross-tile CSE of B-frags

    auto tile = [&](int jt, int last, int pf) {
        _Float16 djh = (_Float16)dj;
        f16x8 dj8;
#pragma unroll
        for (int i = 0; i < 8; ++i) dj8[i] = djh;
        f16x8 A0 = __builtin_elementwise_fma(dj8, wdlo, ulo + vlo);
        f16x8 A1 = __builtin_elementwise_fma(dj8, wdhi, uhi + vhi);
        A0 = __builtin_elementwise_max(A0, (_Float16)0.1f * A0);
        A1 = __builtin_elementwise_max(A1, (_Float16)0.1f * A1);
        if (pf) {  // prefetch next tile into the SAME v regs
            int j = (jt + 1) * 16 + kk;
            int jc = j < NN ? j : NN - 1;
            const _Float16* vr = Vb + jc * 64 + c0;
            vlo = *(const f16x8*)vr;
            vhi = *(const f16x8*)(vr + 32);
            dj = sdist[j];
        }
        asm volatile("" : "+v"(pb));
        const _Float16* pB = (const _Float16*)((const char*)pwl + pb);
#pragma unroll
        for (int kt = 0; kt < 4; ++kt) {
            f16x8 B0 = *(const f16x8*)&pB[(kt * 2 + 0) * 512 + lane * 8];
            f16x8 B1 = *(const f16x8*)&pB[(kt * 2 + 1) * 512 + lane * 8];
            f32x4 a = {0.f, 0.f, 0.f, 0.f};
            a = __builtin_amdgcn_mfma_f32_16x16x32_f16(A0, B0, a, 0, 0, 0);
            a = __builtin_amdgcn_mfma_f32_16x16x32_f16(A1, B1, a, 0, 0, 0);
            f32x4 s4 = a + b1k[kt];
            s4 = __builtin_elementwise_max(s4, 0.1f * s4);
            float hs = hsum4(s4);
            sacc[kt] += last ? hs * m6 : hs;  // mask rows j >= 100 on last tile
        }
    };
    if (w == 0) { tile(0, 0, 1); tile(1, 0, 1); tile(2, 0, 0); }
    else        { tile(3, 0, 1); tile(4, 0, 1); tile(5, 0, 1); tile(6, 1, 0); }

    // per-wave partial agg over its j-half; col kk -> k = kt*16+kk
    {
#pragma unroll
        for (int kt = 0; kt < 4; ++kt) {
            float s = sacc[kt];
            s += __shfl_xor(s, 16);
            s += __shfl_xor(s, 32);
            if (lane < 16) aggp[w][kt * 16 + lane] = s;
        }
    }
    __syncthreads();

    // node MLP layer 0: 128 threads = 64 outputs x 2 input-halves (48 each)
    {
        int k = t & 63, p = t >> 6;
        float sa = 0.f, sb = 0.f;
#pragma unroll
        for (int ii = 0; ii < 48; ii += 2) {
            int c = p * 48 + ii;
            float x0 = (c < 32) ? sxin[c] : (aggp[0][c - 32] + aggp[1][c - 32]);
            float x1 = (c + 1 < 32) ? sxin[c + 1] : (aggp[0][c - 31] + aggp[1][c - 31]);
            sa += x0 * w0n[c * 64 + k];
            sb += x1 * w0n[(c + 1) * 64 + k];
        }
        red[p][k] = sa + sb;
    }
    __syncthreads();
    if (t < 64) st0[t] = lrelu(b0n[t] + red[0][t] + red[1][t]);
    // node MLP layer 1 on wave 0 (reads st0 written by this same wave: in-order)
    if (t < 64) {
        int k2 = lane & 31, p = lane >> 5;
        float sa = 0.f, sb = 0.f;
#pragma unroll
        for (int cc = 0; cc < 32; cc += 2) {
            int c = p * 32 + cc;
            sa += st0[c] * w1n[c * DL + k2];
            sb += st0[c + 1] * w1n[(c + 1) * DL + k2];
        }
        float s = sa + sb;
        s += __shfl_xor(s, 32);
        if (lane < 32) {
            float hv = lrelu(s + b1n[lane]);
            sh2[lane] = hv;
            if (!FINAL) hout[bi * DL + lane] = hv;
        }
    }

    if (FINAL) {
        if (t < 3) {  // wave0; sh2 written by this wave -> in-order
            float s = bA[t];
#pragma unroll
            for (int c = 0; c < DL; ++c) s += sh2[c] * wA[c * 3 + t];
            out[bi * 3 + t] = tanhf(s);
        }
    } else {  // U/V for the next step: wave0 -> U, wave1 -> V (coalesced ew0 layout)
        __syncthreads();
        float s = w ? 0.f : bA[lane];
#pragma unroll
        for (int c = 0; c < DL; ++c) s += sh2[c] * wA[(w * DL + c) * 64 + lane];
        if (w) Vo[bi * 64 + lane] = (_Float16)s;
        else   Uo[bi * 64 + lane] = s;
    }
}

extern "C" void kernel_launch(void* const* d_in, const int* in_sizes, int n_in,
                              void* d_out, int out_size, void* d_ws, size_t ws_size,
                              hipStream_t stream) {
    const float* x     = (const float*)d_in[0];
    const float* lin_w = (const float*)d_in[1];
    const float* lin_b = (const float*)d_in[2];
    const float* ew0[2] = {(const float*)d_in[3],  (const float*)d_in[11]};
    const float* eb0[2] = {(const float*)d_in[4],  (const float*)d_in[12]};
    const float* ew1[2] = {(const float*)d_in[5],  (const float*)d_in[13]};
    const float* eb1[2] = {(const float*)d_in[6],  (const float*)d_in[14]};
    const float* nw0[2] = {(const float*)d_in[7],  (const float*)d_in[15]};
    const float* nb0[2] = {(const float*)d_in[8],  (const float*)d_in[16]};
    const float* nw1[2] = {(const float*)d_in[9],  (const float*)d_in[17]};
    const float* nb1[2] = {(const float*)d_in[10], (const float*)d_in[18]};
    const float* ow = (const float*)d_in[19];
    const float* ob = (const float*)d_in[20];
    float* out = (float*)d_out;

    float* h    = (float*)d_ws;               // 6400 x 32 f32
    float* h2   = h + 204800;                 // 6400 x 32 f32
    float* U    = h2 + 204800;                // 6400 x 64 f32
    float* U2   = U + 409600;                 // 6400 x 64 f32
    _Float16* V  = (_Float16*)(U2 + 409600);  // 6400 x 64 f16
    _Float16* V2 = V + 409600;                // 6400 x 64 f16
    _Float16* PW = V2 + 409600;               // 2 x 4096 f16

    k_pre<<<1602, 256, 0, stream>>>(x, lin_w, lin_b, ew0[0], eb0[0], ew1[0], ew1[1],
                                    h, U, V, PW);
    k_edge<0><<<BN, 128, 0, stream>>>(h, U, V, ew0[0], PW, eb1[0],
                                      nw0[0], nb0[0], nw1[0], nb1[0],
                                      ew0[1], eb0[1], h2, U2, V2, nullptr);
    k_edge<1><<<BN, 128, 0, stream>>>(h2, U2, V2, ew0[1], PW + 4096, eb1[1],
                                      nw0[1], nb0[1], nw1[1], nb1[1],
                                      ow, ob, nullptr, nullptr, nullptr, out);
}

// Round 9
// 195.714 us; speedup vs baseline: 1.0414x; 1.0414x over previous
//
#include <hip/hip_runtime.h>

#define NB 64
#define NN 100
#define DL 32
#define BN (NB * NN)  // 6400

typedef _Float16 f16x8 __attribute__((ext_vector_type(8)));
typedef float f32x4 __attribute__((ext_vector_type(4)));

static __device__ __forceinline__ float lrelu(float x) { return fmaxf(x, 0.1f * x); }
static __device__ __forceinline__ f32x4 ld4(const float* p) { return *(const f32x4*)p; }
static __device__ __forceinline__ float hsum4(f32x4 v) { return v[0] + v[1] + v[2] + v[3]; }

// Fused: h = x@lin_w+lin_b, U/V for step 0 (V stored f16), W1 B-fragment prep.
// Blocks 0..1599: 4 (b,n) rows each. Blocks 1600..1601: PW for step 0/1.
__global__ __launch_bounds__(256) void k_pre(
    const float* __restrict__ x, const float* __restrict__ lw, const float* __restrict__ lb,
    const float* __restrict__ ew0, const float* __restrict__ eb0,
    const float* __restrict__ w1a, const float* __restrict__ w1b,
    float* __restrict__ h, float* __restrict__ U, _Float16* __restrict__ V,
    _Float16* __restrict__ PW) {
    int blk = blockIdx.x;
    int t = threadIdx.x;
    if (blk >= 1600) {  // B-fragment swizzle: PW[step][kt][hf][lane][jj]
        int step = blk - 1600;
        const float* w1 = step ? w1b : w1a;
        _Float16* dst = PW + step * 4096;
#pragma unroll
        for (int u = 0; u < 16; ++u) {
            int idx = t * 16 + u;
            int jj = idx & 7, lane = (idx >> 3) & 63, hf = (idx >> 9) & 1, kt = idx >> 10;
            int c = hf * 32 + (lane >> 4) * 8 + jj;
            int k = kt * 16 + (lane & 15);
            dst[idx] = (_Float16)w1[c * 64 + k];
        }
        return;
    }
    __shared__ float xs[DL];
    __shared__ float hs[4][DL];
    int row0 = blk * 4;
    int b = row0 / NN;  // 4-row group never crosses a batch boundary (100 % 4 == 0)
    if (t < DL) xs[t] = x[b * DL + t];
    __syncthreads();
    if (t < 128) {
        int ni = t >> 5, c = t & 31;
        int n = (row0 + ni) % NN;
        float s = lb[n * DL + c];
#pragma unroll
        for (int cc = 0; cc < DL; ++cc) s += xs[cc] * lw[cc * 3200 + n * DL + c];
        hs[ni][c] = s;
        h[(row0 + ni) * DL + c] = s;
    }
    __syncthreads();
#pragma unroll
    for (int r = 0; r < 2; ++r) {
        int o = r * 256 + t;  // 0..511 : 4 rows x (64 U + 64 V)
        int ni = o >> 7, kw = o & 127;
        int which = kw >> 6, k = kw & 63;
        const float* wp = ew0 + (which ? DL * 64 : 0) + k;
        float s = which ? 0.f : eb0[k];
#pragma unroll
        for (int c = 0; c < DL; ++c) s += hs[ni][c] * wp[c * 64];
        if (which) V[(row0 + ni) * 64 + k] = (_Float16)s;
        else       U[(row0 + ni) * 64 + k] = s;
    }
}

// Per-wave edge+node step with ZERO barriers. R8 lesson: splitting a row across
// barrier-coupled waves regresses (sibling waits + per-row staging overhead).
// v13: drop the pwl LDS staging entirely -- B-fragments are read directly from
// global PW (same 8 KB for every block -> L1-resident after first use per CU).
// This removes the block's only __syncthreads (4 waves fully independent), the
// 512-load staging, and 8 KB/block of LDS. All prior lessons kept: no min-waves
// bound (R4/R5 spill), opaque-offset anti-hoist on the B pointer (R7, keeps the
// 8 B-frags from being hoisted as 32 live VGPRs), packed-f16 P-build + f16 V (R6).
template <int FINAL>
__global__ __launch_bounds__(256) void k_edge(
    const float* __restrict__ h, const float* __restrict__ U, const _Float16* __restrict__ V,
    const float* __restrict__ w0, const _Float16* __restrict__ PW,
    const float* __restrict__ b1,
    const float* __restrict__ w0n, const float* __restrict__ b0n,
    const float* __restrict__ w1n, const float* __restrict__ b1n,
    const float* __restrict__ wA, const float* __restrict__ bA,
    float* __restrict__ hout, float* __restrict__ Uo, _Float16* __restrict__ Vo,
    float* __restrict__ out) {
    __shared__ float sdist[4][112];
    __shared__ __align__(16) float sxin[4][96];  // [0..31]=h_i, [32..95]=agg
    __shared__ __align__(16) float st0[4][64];
    __shared__ __align__(16) float sh2[4][32];

    int t = threadIdx.x;
    int w = t >> 6, lane = t & 63, q = lane >> 4, kk = lane & 15;
    int bi = blockIdx.x * 4 + w;
    int b = bi / NN;

    // h_i -> LDS (wave-local; in-wave LDS ordering via lgkmcnt, no barrier needed)
    if (lane < 32) sxin[w][lane] = h[bi * DL + lane];

    // distances: 8 lanes per j (coalesced 32B chunks), shfl-reduce in the group
    {
        int g = lane >> 3, r = lane & 7;
        f32x4 hi4 = ld4(h + bi * DL + r * 4);
        const float* hb = h + b * NN * DL;
#pragma unroll
        for (int it = 0; it < 14; ++it) {
            int j = it * 8 + g;
            int jc = j < NN ? j : NN - 1;
            f32x4 hj4 = ld4(hb + jc * DL + r * 4);
            f32x4 dd = hi4 - hj4;
            float s = dd[0] * dd[0] + dd[1] * dd[1] + dd[2] * dd[2] + dd[3] * dd[3];
            s += __shfl_xor(s, 1);
            s += __shfl_xor(s, 2);
            s += __shfl_xor(s, 4);
            if (r == 0) sdist[w][j] = sqrtf(s + 1e-12f);
        }
    }

    int c0 = q * 8;  // this lane's channel base
    // u (U_i + b0 folded) and wd as packed f16 (8 VGPRs each)
    f16x8 ulo, uhi, wdlo, wdhi;
    {
        const float* Up = U + (size_t)bi * 64;
        f32x4 a0 = ld4(Up + c0), a1 = ld4(Up + c0 + 4);
        f32x4 a2 = ld4(Up + 32 + c0), a3 = ld4(Up + 36 + c0);
        const float* wd = w0 + 64 * 64;
        f32x4 d0 = ld4(wd + c0), d1 = ld4(wd + c0 + 4);
        f32x4 d2 = ld4(wd + 32 + c0), d3 = ld4(wd + 36 + c0);
#pragma unroll
        for (int i = 0; i < 4; ++i) {
            ulo[i] = (_Float16)a0[i];  ulo[i + 4] = (_Float16)a1[i];
            uhi[i] = (_Float16)a2[i];  uhi[i + 4] = (_Float16)a3[i];
            wdlo[i] = (_Float16)d0[i]; wdlo[i + 4] = (_Float16)d1[i];
            wdhi[i] = (_Float16)d2[i]; wdhi[i + 4] = (_Float16)d3[i];
        }
    }
    float b1k[4];
#pragma unroll
    for (int kt = 0; kt < 4; ++kt) b1k[kt] = b1[kt * 16 + kk];
    float m6 = (q == 0) ? 1.f : 0.f;  // tile 6: only rows 96..99 (q==0) valid

    const _Float16* Vb = V + (size_t)b * NN * 64;
    // prefetch tile 0 (j = kk < 100, no clamp); V rows are f16
    f16x8 vlo, vhi;
    {
        const _Float16* vr = Vb + kk * 64 + c0;
        vlo = *(const f16x8*)vr;
        vhi = *(const f16x8*)(vr + 32);
    }
    float dj = sdist[w][kk];

    float sacc[4] = {0.f, 0.f, 0.f, 0.f};
    unsigned pb = 0;  // opaque byte-offset: blocks cross-tile CSE/hoist of B-frags
#pragma unroll
    for (int jt = 0; jt < 7; ++jt) {
        // P build in packed f16: result is exactly this lane's A-fragments
        _Float16 djh = (_Float16)dj;
        f16x8 dj8;
#pragma unroll
        for (int i = 0; i < 8; ++i) dj8[i] = djh;
        f16x8 A0 = __builtin_elementwise_fma(dj8, wdlo, ulo + vlo);
        f16x8 A1 = __builtin_elementwise_fma(dj8, wdhi, uhi + vhi);
        A0 = __builtin_elementwise_max(A0, (_Float16)0.1f * A0);
        A1 = __builtin_elementwise_max(A1, (_Float16)0.1f * A1);

        if (jt < 6) {  // prefetch next tile into the SAME v regs (in-order issue)
            int j = (jt + 1) * 16 + kk;
            int jc = (jt == 5 && j >= NN) ? NN - 1 : j;
            const _Float16* vr = Vb + jc * 64 + c0;
            vlo = *(const f16x8*)vr;
            vhi = *(const f16x8*)(vr + 32);
            dj = sdist[w][j];
        }
        // B-frags straight from global PW (L1-hot: same 8 KB for every block).
        // Opaque offset -> the 8 16B loads live only inside this jt body.
        asm volatile("" : "+v"(pb));
        const _Float16* pB = (const _Float16*)((const char*)PW + pb);
#pragma unroll
        for (int kt = 0; kt < 4; ++kt) {
            f16x8 B0 = *(const f16x8*)&pB[(kt * 2 + 0) * 512 + lane * 8];
            f16x8 B1 = *(const f16x8*)&pB[(kt * 2 + 1) * 512 + lane * 8];
            f32x4 a = {0.f, 0.f, 0.f, 0.f};
            a = __builtin_amdgcn_mfma_f32_16x16x32_f16(A0, B0, a, 0, 0, 0);
            a = __builtin_amdgcn_mfma_f32_16x16x32_f16(A1, B1, a, 0, 0, 0);
            f32x4 s4 = a + b1k[kt];
            s4 = __builtin_elementwise_max(s4, 0.1f * s4);
            float hs = hsum4(s4);
            sacc[kt] += (jt == 6) ? hs * m6 : hs;  // mask rows j >= 100 on last tile
        }
    }

    // agg[k]: reduce across q groups; col kk -> k = kt*16+kk
    {
        float ag[4];
#pragma unroll
        for (int kt = 0; kt < 4; ++kt) {
            float s = sacc[kt];
            s += __shfl_xor(s, 16);
            s += __shfl_xor(s, 32);
            ag[kt] = s;
        }
        if (lane < 16) {
#pragma unroll
            for (int kt = 0; kt < 4; ++kt) sxin[w][32 + kt * 16 + lane] = ag[kt];
        }
    }

    // node MLP layer 0: lane = output k, coalesced w0n[c*64+k], LDS broadcast input
    {
        float sa = 0.f, sb = 0.f, sc = 0.f, sd = 0.f;
#pragma unroll
        for (int c = 0; c < 96; c += 4) {
            sa += sxin[w][c + 0] * w0n[(c + 0) * 64 + lane];
            sb += sxin[w][c + 1] * w0n[(c + 1) * 64 + lane];
            sc += sxin[w][c + 2] * w0n[(c + 2) * 64 + lane];
            sd += sxin[w][c + 3] * w0n[(c + 3) * 64 + lane];
        }
        st0[w][lane] = lrelu((sa + sb) + (sc + sd) + b0n[lane]);
    }
    // node MLP layer 1: k = lane&31, half p = lane>>5, shfl-combine
    {
        int k2 = lane & 31, p = lane >> 5;
        float sa = 0.f, sb = 0.f;
#pragma unroll
        for (int cc = 0; cc < 32; cc += 2) {
            int c = p * 32 + cc;
            sa += st0[w][c] * w1n[c * DL + k2];
            sb += st0[w][c + 1] * w1n[(c + 1) * DL + k2];
        }
        float s = sa + sb;
        s += __shfl_xor(s, 32);
        if (lane < 32) {
            float hv = lrelu(s + b1n[lane]);
            sh2[w][lane] = hv;
            if (!FINAL) hout[bi * DL + lane] = hv;
        }
    }

    if (FINAL) {
        if (lane < 3) {
            float s = bA[lane];
#pragma unroll
            for (int c = 0; c < DL; ++c) s += sh2[w][c] * wA[c * 3 + lane];
            out[bi * 3 + lane] = tanhf(s);
        }
    } else {  // U/V for the next step (coalesced ew0 layout); V stored f16
        float su = bA[lane], sv = 0.f;
#pragma unroll
        for (int c = 0; c < DL; ++c) {
            float hv = sh2[w][c];
            su += hv * wA[c * 64 + lane];
            sv += hv * wA[(DL + c) * 64 + lane];
        }
        Uo[bi * 64 + lane] = su;
        Vo[bi * 64 + lane] = (_Float16)sv;
    }
}

extern "C" void kernel_launch(void* const* d_in, const int* in_sizes, int n_in,
                              void* d_out, int out_size, void* d_ws, size_t ws_size,
                              hipStream_t stream) {
    const float* x     = (const float*)d_in[0];
    const float* lin_w = (const float*)d_in[1];
    const float* lin_b = (const float*)d_in[2];
    const float* ew0[2] = {(const float*)d_in[3],  (const float*)d_in[11]};
    const float* eb0[2] = {(const float*)d_in[4],  (const float*)d_in[12]};
    const float* ew1[2] = {(const float*)d_in[5],  (const float*)d_in[13]};
    const float* eb1[2] = {(const float*)d_in[6],  (const float*)d_in[14]};
    const float* nw0[2] = {(const float*)d_in[7],  (const float*)d_in[15]};
    const float* nb0[2] = {(const float*)d_in[8],  (const float*)d_in[16]};
    const float* nw1[2] = {(const float*)d_in[9],  (const float*)d_in[17]};
    const float* nb1[2] = {(const float*)d_in[10], (const float*)d_in[18]};
    const float* ow = (const float*)d_in[19];
    const float* ob = (const float*)d_in[20];
    float* out = (float*)d_out;

    float* h    = (float*)d_ws;               // 6400 x 32 f32
    float* h2   = h + 204800;                 // 6400 x 32 f32
    float* U    = h2 + 204800;                // 6400 x 64 f32
    float* U2   = U + 409600;                 // 6400 x 64 f32
    _Float16* V  = (_Float16*)(U2 + 409600);  // 6400 x 64 f16
    _Float16* V2 = V + 409600;                // 6400 x 64 f16
    _Float16* PW = V2 + 409600;               // 2 x 4096 f16

    k_pre<<<1602, 256, 0, stream>>>(x, lin_w, lin_b, ew0[0], eb0[0], ew1[0], ew1[1],
                                    h, U, V, PW);
    k_edge<0><<<1600, 256, 0, stream>>>(h, U, V, ew0[0], PW, eb1[0],
                                        nw0[0], nb0[0], nw1[0], nb1[0],
                                        ew0[1], eb0[1], h2, U2, V2, nullptr);
    k_edge<1><<<1600, 256, 0, stream>>>(h2, U2, V2, ew0[1], PW + 4096, eb1[1],
                                        nw0[1], nb0[1], nw1[1], nb1[1],
                                        ow, ob, nullptr, nullptr, nullptr, out);
}

// Round 10
// 161.915 us; speedup vs baseline: 1.2588x; 1.2087x over previous
//
#include <hip/hip_runtime.h>

#define NB 64
#define NN 100
#define DL 32
#define BN (NB * NN)  // 6400

typedef _Float16 f16x8 __attribute__((ext_vector_type(8)));
typedef float f32x4 __attribute__((ext_vector_type(4)));

static __device__ __forceinline__ float lrelu(float x) { return fmaxf(x, 0.1f * x); }
static __device__ __forceinline__ f32x4 ld4(const float* p) { return *(const f32x4*)p; }
static __device__ __forceinline__ float hsum4(f32x4 v) { return v[0] + v[1] + v[2] + v[3]; }

// Fused: h = x@lin_w+lin_b, U/V for step 0 (V stored f16), W1 B-fragment prep.
// Blocks 0..1599: 4 (b,n) rows each. Blocks 1600..1601: PW for step 0/1.
__global__ __launch_bounds__(256) void k_pre(
    const float* __restrict__ x, const float* __restrict__ lw, const float* __restrict__ lb,
    const float* __restrict__ ew0, const float* __restrict__ eb0,
    const float* __restrict__ w1a, const float* __restrict__ w1b,
    float* __restrict__ h, float* __restrict__ U, _Float16* __restrict__ V,
    _Float16* __restrict__ PW) {
    int blk = blockIdx.x;
    int t = threadIdx.x;
    if (blk >= 1600) {  // B-fragment swizzle: PW[step][kt][hf][lane][jj]
        int step = blk - 1600;
        const float* w1 = step ? w1b : w1a;
        _Float16* dst = PW + step * 4096;
#pragma unroll
        for (int u = 0; u < 16; ++u) {
            int idx = t * 16 + u;
            int jj = idx & 7, lane = (idx >> 3) & 63, hf = (idx >> 9) & 1, kt = idx >> 10;
            int c = hf * 32 + (lane >> 4) * 8 + jj;
            int k = kt * 16 + (lane & 15);
            dst[idx] = (_Float16)w1[c * 64 + k];
        }
        return;
    }
    __shared__ float xs[DL];
    __shared__ float hs[4][DL];
    int row0 = blk * 4;
    int b = row0 / NN;  // 4-row group never crosses a batch boundary (100 % 4 == 0)
    if (t < DL) xs[t] = x[b * DL + t];
    __syncthreads();
    if (t < 128) {
        int ni = t >> 5, c = t & 31;
        int n = (row0 + ni) % NN;
        float s = lb[n * DL + c];
#pragma unroll
        for (int cc = 0; cc < DL; ++cc) s += xs[cc] * lw[cc * 3200 + n * DL + c];
        hs[ni][c] = s;
        h[(row0 + ni) * DL + c] = s;
    }
    __syncthreads();
#pragma unroll
    for (int r = 0; r < 2; ++r) {
        int o = r * 256 + t;  // 0..511 : 4 rows x (64 U + 64 V)
        int ni = o >> 7, kw = o & 127;
        int which = kw >> 6, k = kw & 63;
        const float* wp = ew0 + (which ? DL * 64 : 0) + k;
        float s = which ? 0.f : eb0[k];
#pragma unroll
        for (int c = 0; c < DL; ++c) s += hs[ni][c] * wp[c * 64];
        if (which) V[(row0 + ni) * 64 + k] = (_Float16)s;
        else       U[(row0 + ni) * 64 + k] = s;
    }
}

// Per-wave edge+node step, ONE barrier (R7 structure -- best measured: 41.1us).
// R8: row-split across waves regresses (barrier coupling). R9: B-frags from
// global regress (vmcnt latency vs LDS lgkmcnt). This version = R7 + VALU cuts:
//   - dist: 4 lanes/j, f32x4 x2 per lane, 2 shfl (was 8 lanes/j, 3 shfl)
//   - epilogue LDS inputs read via explicit ld4 (ds_read_b128 batching)
// Kept: no min-waves bound (R4/R5 spill), opaque-pb anti-hoist (R7),
// packed-f16 P-build + f16 V (R6), LDS pwl staging (R9).
template <int FINAL>
__global__ __launch_bounds__(256) void k_edge(
    const float* __restrict__ h, const float* __restrict__ U, const _Float16* __restrict__ V,
    const float* __restrict__ w0, const _Float16* __restrict__ PW,
    const float* __restrict__ b1,
    const float* __restrict__ w0n, const float* __restrict__ b0n,
    const float* __restrict__ w1n, const float* __restrict__ b1n,
    const float* __restrict__ wA, const float* __restrict__ bA,
    float* __restrict__ hout, float* __restrict__ Uo, _Float16* __restrict__ Vo,
    float* __restrict__ out) {
    __shared__ __align__(16) _Float16 pwl[4096];
    __shared__ float sdist[4][112];
    __shared__ __align__(16) float sxin[4][96];  // [0..31]=h_i, [32..95]=agg
    __shared__ __align__(16) float st0[4][64];
    __shared__ __align__(16) float sh2[4][32];

    int t = threadIdx.x;
    {  // stage W1 B-fragments once for the whole block
        const f16x8* srcp = (const f16x8*)PW;
        f16x8* dstp = (f16x8*)pwl;
        dstp[t] = srcp[t];
        dstp[t + 256] = srcp[t + 256];
    }
    int w = t >> 6, lane = t & 63, q = lane >> 4, kk = lane & 15;
    int bi = blockIdx.x * 4 + w;
    int b = bi / NN;

    // h_i -> LDS (wave-local; read later via broadcast in the node MLP)
    if (lane < 32) sxin[w][lane] = h[bi * DL + lane];

    // distances: 4 lanes per j (16 j per iter, 7 iters), 32B/lane coalesced,
    // 2-step shfl reduce. All sdist writes complete before the barrier below.
    {
        int g = lane >> 2, r = lane & 3;
        const float* hi = h + bi * DL + r * 8;
        f32x4 hi0 = ld4(hi), hi1 = ld4(hi + 4);
        const float* hb = h + b * NN * DL;
#pragma unroll
        for (int it = 0; it < 7; ++it) {
            int j = it * 16 + g;
            int jc = j < NN ? j : NN - 1;
            const float* hj = hb + jc * DL + r * 8;
            f32x4 d0 = hi0 - ld4(hj);
            f32x4 d1 = hi1 - ld4(hj + 4);
            f32x4 s4 = d0 * d0 + d1 * d1;
            float s = hsum4(s4);
            s += __shfl_xor(s, 1);
            s += __shfl_xor(s, 2);
            if (r == 0) sdist[w][j] = sqrtf(s + 1e-12f);
        }
    }

    int c0 = q * 8;  // this lane's channel base
    // u (U_i + b0 folded) and wd as packed f16 (8 VGPRs each)
    f16x8 ulo, uhi, wdlo, wdhi;
    {
        const float* Up = U + (size_t)bi * 64;
        f32x4 a0 = ld4(Up + c0), a1 = ld4(Up + c0 + 4);
        f32x4 a2 = ld4(Up + 32 + c0), a3 = ld4(Up + 36 + c0);
        const float* wd = w0 + 64 * 64;
        f32x4 d0 = ld4(wd + c0), d1 = ld4(wd + c0 + 4);
        f32x4 d2 = ld4(wd + 32 + c0), d3 = ld4(wd + 36 + c0);
#pragma unroll
        for (int i = 0; i < 4; ++i) {
            ulo[i] = (_Float16)a0[i];  ulo[i + 4] = (_Float16)a1[i];
            uhi[i] = (_Float16)a2[i];  uhi[i + 4] = (_Float16)a3[i];
            wdlo[i] = (_Float16)d0[i]; wdlo[i + 4] = (_Float16)d1[i];
            wdhi[i] = (_Float16)d2[i]; wdhi[i + 4] = (_Float16)d3[i];
        }
    }
    float b1k[4];
#pragma unroll
    for (int kt = 0; kt < 4; ++kt) b1k[kt] = b1[kt * 16 + kk];
    float m6 = (q == 0) ? 1.f : 0.f;  // tile 6: only rows 96..99 (q==0) valid

    const _Float16* Vb = V + (size_t)b * NN * 64;
    // prefetch tile 0 (j = kk < 100, no clamp); V rows are f16
    f16x8 vlo, vhi;
    {
        const _Float16* vr = Vb + kk * 64 + c0;
        vlo = *(const f16x8*)vr;
        vhi = *(const f16x8*)(vr + 32);
    }

    __syncthreads();  // pwl ready
    float dj = sdist[w][kk];

    float sacc[4] = {0.f, 0.f, 0.f, 0.f};
    unsigned pb = 0;  // opaque LDS byte-offset: re-defined each jt by the asm nop
#pragma unroll
    for (int jt = 0; jt < 7; ++jt) {
        // P build in packed f16: result is exactly this lane's A-fragments
        _Float16 djh = (_Float16)dj;
        f16x8 dj8;
#pragma unroll
        for (int i = 0; i < 8; ++i) dj8[i] = djh;
        f16x8 A0 = __builtin_elementwise_fma(dj8, wdlo, ulo + vlo);
        f16x8 A1 = __builtin_elementwise_fma(dj8, wdhi, uhi + vhi);
        A0 = __builtin_elementwise_max(A0, (_Float16)0.1f * A0);
        A1 = __builtin_elementwise_max(A1, (_Float16)0.1f * A1);

        if (jt < 6) {  // prefetch next tile into the SAME v regs (in-order issue)
            int j = (jt + 1) * 16 + kk;
            int jc = (jt == 5 && j >= NN) ? NN - 1 : j;
            const _Float16* vr = Vb + jc * 64 + c0;
            vlo = *(const f16x8*)vr;
            vhi = *(const f16x8*)(vr + 32);
            dj = sdist[w][j];
        }
        // Opaque base: compiler cannot CSE/hoist the 8 B-frag ds_reads across
        // jt iterations -> they stay inside this body (peak +8 regs, not +32).
        asm volatile("" : "+v"(pb));
        const _Float16* pB = (const _Float16*)((const char*)pwl + pb);
#pragma unroll
        for (int kt = 0; kt < 4; ++kt) {
            f16x8 B0 = *(const f16x8*)&pB[(kt * 2 + 0) * 512 + lane * 8];
            f16x8 B1 = *(const f16x8*)&pB[(kt * 2 + 1) * 512 + lane * 8];
            f32x4 a = {0.f, 0.f, 0.f, 0.f};
            a = __builtin_amdgcn_mfma_f32_16x16x32_f16(A0, B0, a, 0, 0, 0);
            a = __builtin_amdgcn_mfma_f32_16x16x32_f16(A1, B1, a, 0, 0, 0);
            f32x4 s4 = a + b1k[kt];
            s4 = __builtin_elementwise_max(s4, 0.1f * s4);
            float hs = hsum4(s4);
            sacc[kt] += (jt == 6) ? hs * m6 : hs;  // mask rows j >= 100 on last tile
        }
    }

    // agg[k]: reduce across q groups; col kk -> k = kt*16+kk
    {
        float ag[4];
#pragma unroll
        for (int kt = 0; kt < 4; ++kt) {
            float s = sacc[kt];
            s += __shfl_xor(s, 16);
            s += __shfl_xor(s, 32);
            ag[kt] = s;
        }
        if (lane < 16) {
#pragma unroll
            for (int kt = 0; kt < 4; ++kt) sxin[w][32 + kt * 16 + lane] = ag[kt];
        }
    }

    // node MLP layer 0: lane = output k, coalesced w0n[c*64+k];
    // inputs batched as ds_read_b128 via ld4
    {
        float sa = 0.f, sb = 0.f, sc = 0.f, sd = 0.f;
#pragma unroll
        for (int c4 = 0; c4 < 24; ++c4) {
            f32x4 xv = ld4(&sxin[w][c4 * 4]);
            sa += xv[0] * w0n[(c4 * 4 + 0) * 64 + lane];
            sb += xv[1] * w0n[(c4 * 4 + 1) * 64 + lane];
            sc += xv[2] * w0n[(c4 * 4 + 2) * 64 + lane];
            sd += xv[3] * w0n[(c4 * 4 + 3) * 64 + lane];
        }
        st0[w][lane] = lrelu((sa + sb) + (sc + sd) + b0n[lane]);
    }
    // node MLP layer 1: k = lane&31, half p = lane>>5, shfl-combine; ld4 inputs
    {
        int k2 = lane & 31, p = lane >> 5;
        float sa = 0.f, sb = 0.f, sc = 0.f, sd = 0.f;
#pragma unroll
        for (int c4 = 0; c4 < 8; ++c4) {
            f32x4 xv = ld4(&st0[w][p * 32 + c4 * 4]);
            int c = p * 32 + c4 * 4;
            sa += xv[0] * w1n[(c + 0) * DL + k2];
            sb += xv[1] * w1n[(c + 1) * DL + k2];
            sc += xv[2] * w1n[(c + 2) * DL + k2];
            sd += xv[3] * w1n[(c + 3) * DL + k2];
        }
        float s = (sa + sb) + (sc + sd);
        s += __shfl_xor(s, 32);
        if (lane < 32) {
            float hv = lrelu(s + b1n[lane]);
            sh2[w][lane] = hv;
            if (!FINAL) hout[bi * DL + lane] = hv;
        }
    }

    if (FINAL) {
        if (lane < 3) {
            float s = bA[lane];
#pragma unroll
            for (int c4 = 0; c4 < 8; ++c4) {
                f32x4 xv = ld4(&sh2[w][c4 * 4]);
#pragma unroll
                for (int i = 0; i < 4; ++i) s += xv[i] * wA[(c4 * 4 + i) * 3 + lane];
            }
            out[bi * 3 + lane] = tanhf(s);
        }
    } else {  // U/V for the next step (coalesced ew0 layout); V stored f16; ld4 inputs
        float su = bA[lane], sv = 0.f;
#pragma unroll
        for (int c4 = 0; c4 < 8; ++c4) {
            f32x4 xv = ld4(&sh2[w][c4 * 4]);
#pragma unroll
            for (int i = 0; i < 4; ++i) {
                int c = c4 * 4 + i;
                su += xv[i] * wA[c * 64 + lane];
                sv += xv[i] * wA[(DL + c) * 64 + lane];
            }
        }
        Uo[bi * 64 + lane] = su;
        Vo[bi * 64 + lane] = (_Float16)sv;
    }
}

extern "C" void kernel_launch(void* const* d_in, const int* in_sizes, int n_in,
                              void* d_out, int out_size, void* d_ws, size_t ws_size,
                              hipStream_t stream) {
    const float* x     = (const float*)d_in[0];
    const float* lin_w = (const float*)d_in[1];
    const float* lin_b = (const float*)d_in[2];
    const float* ew0[2] = {(const float*)d_in[3],  (const float*)d_in[11]};
    const float* eb0[2] = {(const float*)d_in[4],  (const float*)d_in[12]};
    const float* ew1[2] = {(const float*)d_in[5],  (const float*)d_in[13]};
    const float* eb1[2] = {(const float*)d_in[6],  (const float*)d_in[14]};
    const float* nw0[2] = {(const float*)d_in[7],  (const float*)d_in[15]};
    const float* nb0[2] = {(const float*)d_in[8],  (const float*)d_in[16]};
    const float* nw1[2] = {(const float*)d_in[9],  (const float*)d_in[17]};
    const float* nb1[2] = {(const float*)d_in[10], (const float*)d_in[18]};
    const float* ow = (const float*)d_in[19];
    const float* ob = (const float*)d_in[20];
    float* out = (float*)d_out;

    float* h    = (float*)d_ws;               // 6400 x 32 f32
    float* h2   = h + 204800;                 // 6400 x 32 f32
    float* U    = h2 + 204800;                // 6400 x 64 f32
    float* U2   = U + 409600;                 // 6400 x 64 f32
    _Float16* V  = (_Float16*)(U2 + 409600);  // 6400 x 64 f16
    _Float16* V2 = V + 409600;                // 6400 x 64 f16
    _Float16* PW = V2 + 409600;               // 2 x 4096 f16

    k_pre<<<1602, 256, 0, stream>>>(x, lin_w, lin_b, ew0[0], eb0[0], ew1[0], ew1[1],
                                    h, U, V, PW);
    k_edge<0><<<1600, 256, 0, stream>>>(h, U, V, ew0[0], PW, eb1[0],
                                        nw0[0], nb0[0], nw1[0], nb1[0],
                                        ew0[1], eb0[1], h2, U2, V2, nullptr);
    k_edge<1><<<1600, 256, 0, stream>>>(h2, U2, V2, ew0[1], PW + 4096, eb1[1],
                                        nw0[1], nb0[1], nw1[1], nb1[1],
                                        ow, ob, nullptr, nullptr, nullptr, out);
}